// Round 12
// baseline (189.576 us; speedup 1.0000x reference)
//
#include <hip/hip_runtime.h>
#include <hip/hip_bf16.h>

#define SEQ 2048
#define BATCH 4
#define HID 1024

typedef __bf16 bf16x8 __attribute__((ext_vector_type(8)));
typedef float f32x4 __attribute__((ext_vector_type(4)));

__device__ __forceinline__ void gload_lds16(void* lds, const void* g) {
  __builtin_amdgcn_global_load_lds(
      (const __attribute__((address_space(1))) void*)g,
      (__attribute__((address_space(3))) void*)lds, 16, 0, 0);
}

// ---------------- merged prep: cast x, cast Wq/Wk/Wv, concat bias ----------------
__device__ __forceinline__ void cast8(const float* __restrict__ in,
                                      __bf16* __restrict__ out, int i) {
  const float4* p = (const float4*)in + (size_t)i * 2;
  float4 a = p[0], b = p[1];
  bf16x8 v;
  v[0] = (__bf16)a.x; v[1] = (__bf16)a.y; v[2] = (__bf16)a.z; v[3] = (__bf16)a.w;
  v[4] = (__bf16)b.x; v[5] = (__bf16)b.y; v[6] = (__bf16)b.z; v[7] = (__bf16)b.w;
  ((bf16x8*)out)[i] = v;
}

#define NX (SEQ * BATCH * HID / 8)   // 1,048,576
#define NWI (HID * HID / 8)          // 131,072

__global__ __launch_bounds__(256) void prep(const float* __restrict__ x,
                                            const float* __restrict__ Wq,
                                            const float* __restrict__ Wk,
                                            const float* __restrict__ Wv,
                                            const float* __restrict__ bq,
                                            const float* __restrict__ bk,
                                            const float* __restrict__ bv,
                                            __bf16* __restrict__ xbf,
                                            __bf16* __restrict__ wqkv,
                                            float* __restrict__ bqkv) {
  int id = blockIdx.x * 256 + threadIdx.x;
  if (id < NX) {
    cast8(x, xbf, id);
  } else if (id < NX + 3 * NWI) {
    const int j = id - NX;
    const int w = j / NWI, k = j - w * NWI;
    const float* src = w == 0 ? Wq : w == 1 ? Wk : Wv;
    cast8(src, wqkv + (size_t)w * HID * HID, k);
  } else if (id < NX + 3 * NWI + 3 * HID) {
    const int j = id - (NX + 3 * NWI);
    bqkv[j] = j < HID ? bq[j] : j < 2 * HID ? bk[j - HID] : bv[j - 2 * HID];
  }
}

// ====== 128x128xBK32 B^T GEMM, 4 waves (2x2), ring-3 (48KB) => 3 blocks/CU ======
// One barrier/K-tile; counted vmcnt(4) steady (0 only on last tile).
// CYCLIC chunk swizzle (fixes R9's 4-way conflict): LDS[row][j] holds global
// chunk (j + (row>>2)) & 3; read chunk j = (fq - (row>>2)) & 3. Per 16-lane
// issue phase every bank-slot is hit exactly 2x (free, m136).
// EPI 0: QKV, M flat 8192 (row = s*4+b); EPI 2: exp-scores + 16-wide partials;
// EPI 3: PV / rowsum.
#define SL 16384  // A 128x32x2 = 8KB | B 8KB
template<int EPI>
__global__ __launch_bounds__(256, 3)
void gemm97(const __bf16* __restrict__ A, int lda, long long sAz,
            const __bf16* __restrict__ B, int ldb, long long sBz,
            const float* __restrict__ aux, void* __restrict__ dst,
            float* __restrict__ aux2, int K)
{
  __shared__ __align__(16) char lds[3 * SL];
  const int tid = threadIdx.x;
  const int wid = tid >> 6, lane = tid & 63;
  const int wr = wid >> 1, wc = wid & 1;      // 2x2 wave grid, 64x64 tiles
  const int m0 = blockIdx.x * 128, n0 = blockIdx.y * 128;
  const int z = blockIdx.z;
  const __bf16* Ab = A + (size_t)z * sAz;
  const __bf16* Bb = B + (size_t)z * sBz;

  // staging: linear LDS dest (tid*16) = (row=tid>>2, chunk j=tid&3);
  // source global chunk = (j + (row>>2)) & 3  [row>>2 == (tid>>4)&... mod 4]
  const int srow = tid >> 2;                                        // 0..63
  const int scol = (((tid & 3) + ((tid >> 4) & 3)) & 3) * 16;       // source byte col
  const char* a0s = (const char*)(Ab + (size_t)(m0 + srow) * lda) + scol;
  const char* a1s = (const char*)(Ab + (size_t)(m0 + 64 + srow) * lda) + scol;
  const char* b0s = (const char*)(Bb + (size_t)(n0 + srow) * ldb) + scol;
  const char* b1s = (const char*)(Bb + (size_t)(n0 + 64 + srow) * ldb) + scol;
  const int dT = tid * 16;

  auto stage = [&](int slot, int t) {
    char* sb = lds + slot * SL;
    const size_t ko = (size_t)t * 64;          // BK=32 bf16 = 64 B
    gload_lds16(sb + dT, a0s + ko);
    gload_lds16(sb + 4096 + dT, a1s + ko);
    gload_lds16(sb + 8192 + dT, b0s + ko);
    gload_lds16(sb + 12288 + dT, b1s + ko);
  };

  // read: row*64 + ((fq - (fr>>2)) & 3) * 16   [(row>>2)&3 == (fr>>2) here]
  const int fr = lane & 15, fq = lane >> 4;
  const int cc = (((fq - (fr >> 2)) & 3) & 3) * 16;
  int aoff[4], boff[4];
#pragma unroll
  for (int mi = 0; mi < 4; ++mi)
    aoff[mi] = (wr * 64 + mi * 16 + fr) * 64 + cc;
#pragma unroll
  for (int ni = 0; ni < 4; ++ni)
    boff[ni] = 8192 + (wc * 64 + ni * 16 + fr) * 64 + cc;

  const int nk = K >> 5;
  stage(0, 0);
  stage(1, 1);

  f32x4 acc[4][4] = {};
  for (int t = 0; t < nk; ++t) {
    char* s = lds + (t % 3) * SL;
    // drain tile t's 4 loads; keep tile t+1's in flight
    if (t + 1 < nk) asm volatile("s_waitcnt vmcnt(4)" ::: "memory");
    else            asm volatile("s_waitcnt vmcnt(0)" ::: "memory");
    __builtin_amdgcn_s_barrier();
    asm volatile("" ::: "memory");

    bf16x8 a[4], b[4];
#pragma unroll
    for (int mi = 0; mi < 4; ++mi) a[mi] = *(const bf16x8*)(s + aoff[mi]);
#pragma unroll
    for (int ni = 0; ni < 4; ++ni) b[ni] = *(const bf16x8*)(s + boff[ni]);

    // stage t+2 into slot (t+2)%3 == (t-1)%3: consumed reads provably complete
    if (t + 2 < nk) stage((t + 2) % 3, t + 2);

#pragma unroll
    for (int mi = 0; mi < 4; ++mi)
#pragma unroll
      for (int ni = 0; ni < 4; ++ni)
        acc[mi][ni] = __builtin_amdgcn_mfma_f32_16x16x32_bf16(a[mi], b[ni], acc[mi][ni], 0, 0, 0);
  }
  __syncthreads();  // all waves done (last tile waited vmcnt(0)) before LDS reuse

  // ---- epilogues; D frag: row=(lane>>4)*4+r, col=lane&15 ----
  if (EPI == 0) {
    const int hsel = n0 >> 10;  // block-uniform: 0=Q,1=K,2=V
    const size_t BSH = (size_t)BATCH * SEQ * HID;
#pragma unroll
    for (int mi = 0; mi < 4; ++mi) {
#pragma unroll
      for (int ni = 0; ni < 4; ++ni) {
        const int gn = n0 + wc * 64 + ni * 16 + fr;
        const int h = gn & (HID - 1);
        const int gmb = m0 + wr * 64 + mi * 16 + fq * 4;
        const float bias = aux[gn];
        f32x4 v = acc[mi][ni];
#pragma unroll
        for (int r = 0; r < 4; ++r) {
          const int gm = gmb + r;              // flat row = s*BATCH+b
          const int b = gm & 3, sfl = gm >> 2;
          if (hsel < 2)
            ((__bf16*)dst)[(size_t)hsel * BSH + (size_t)b * SEQ * HID +
                           (size_t)sfl * HID + h] = (__bf16)(v[r] + bias);
          else
            ((__bf16*)dst)[2 * BSH + (size_t)b * HID * SEQ +
                           (size_t)h * SEQ + sfl] = (__bf16)(v[r] + bias);
        }
      }
    }
  } else if (EPI == 2) {
    float psum[4][4] = {};
#pragma unroll
    for (int mi = 0; mi < 4; ++mi) {
#pragma unroll
      for (int ni = 0; ni < 4; ++ni) {
        const int gn = n0 + wc * 64 + ni * 16 + fr;
        const int gmb = m0 + wr * 64 + mi * 16 + fq * 4;
        f32x4 v = acc[mi][ni];
#pragma unroll
        for (int r = 0; r < 4; ++r) {
          const size_t idx = (size_t)z * SEQ * SEQ + (size_t)(gmb + r) * SEQ + gn;
          const float e = __expf(v[r] * 0.03125f * aux[idx]);
          ((__bf16*)dst)[idx] = (__bf16)e;
          psum[mi][r] += e;
        }
      }
    }
#pragma unroll
    for (int mi = 0; mi < 4; ++mi)
#pragma unroll
      for (int r = 0; r < 4; ++r) {
        float sv = psum[mi][r];
        sv += __shfl_xor(sv, 1); sv += __shfl_xor(sv, 2);
        sv += __shfl_xor(sv, 4); sv += __shfl_xor(sv, 8);
        psum[mi][r] = sv;
      }
    float* red = (float*)lds;   // [2 wc][128 rows]
    if (fr == 0) {
#pragma unroll
      for (int mi = 0; mi < 4; ++mi)
#pragma unroll
        for (int r = 0; r < 4; ++r)
          red[wc * 128 + wr * 64 + mi * 16 + fq * 4 + r] = psum[mi][r];
    }
    __syncthreads();
    if (tid < 128) {
      const float sv = red[tid] + red[128 + tid];
      aux2[((size_t)z * SEQ + m0 + tid) * 16 + blockIdx.y] = sv;
    }
  } else {  // EPI == 3
    float* red = (float*)lds;
    if (tid < 128) {
      const float* pp = aux + ((size_t)z * SEQ + m0 + tid) * 16;
      float sv = 0.f;
#pragma unroll
      for (int j = 0; j < 16; ++j) sv += pp[j];
      red[tid] = 1.f / sv;
    }
    __syncthreads();
#pragma unroll
    for (int mi = 0; mi < 4; ++mi) {
#pragma unroll
      for (int ni = 0; ni < 4; ++ni) {
        const int gn = n0 + wc * 64 + ni * 16 + fr;
        const int rbase = wr * 64 + mi * 16 + fq * 4;
        f32x4 v = acc[mi][ni];
#pragma unroll
        for (int r = 0; r < 4; ++r)
          ((float*)dst)[((size_t)(m0 + rbase + r) * BATCH + z) * HID + gn] = v[r] * red[rbase + r];
      }
    }
  }
}

extern "C" void kernel_launch(void* const* d_in, const int* in_sizes, int n_in,
                              void* d_out, int out_size, void* d_ws, size_t ws_size,
                              hipStream_t stream) {
  const float* x   = (const float*)d_in[0];
  const float* ssm = (const float*)d_in[1];
  const float* Wq  = (const float*)d_in[2];
  const float* bq  = (const float*)d_in[3];
  const float* Wk  = (const float*)d_in[4];
  const float* bk  = (const float*)d_in[5];
  const float* Wv  = (const float*)d_in[6];
  const float* bv  = (const float*)d_in[7];
  float* out = (float*)d_out;

  const size_t BSH = (size_t)BATCH * SEQ * HID;
  float* bqkv    = (float*)d_ws;                               // 4096 floats
  float* partial = bqkv + 4096;                                // BATCH*SEQ*16
  __bf16* xbf  = (__bf16*)(partial + (size_t)BATCH * SEQ * 16);
  __bf16* wqkv = xbf + BSH;
  __bf16* Qb = wqkv + (size_t)3 * HID * HID;                   // Q | K | Vt
  __bf16* Kb = Qb + BSH;
  __bf16* Vt = Qb + 2 * BSH;
  __bf16* E  = Qb + 3 * BSH;                                   // [b][q][k] bf16

  const int prep_items = NX + 3 * NWI + 3 * HID;
  prep<<<(prep_items + 255) / 256, 256, 0, stream>>>(x, Wq, Wk, Wv, bq, bk, bv,
                                                     xbf, wqkv, bqkv);

  // QKV: M = 8192 flat rows of xbf (row = s*4+b), N = 3072, K = 1024
  gemm97<0><<<dim3(64, 24, 1), 256, 0, stream>>>(xbf, HID, 0,
                                                 wqkv, HID, 0, bqkv, Qb, nullptr, HID);
  // scores: per z, 2048 x 2048 x 1024; E = exp(QK/32 * ssm) + row partials
  gemm97<2><<<dim3(16, 16, 4), 256, 0, stream>>>(Qb, HID, (long long)SEQ * HID,
                                                 Kb, HID, (long long)SEQ * HID,
                                                 ssm, E, partial, HID);
  // PV: per z, 2048 x 1024 x 2048; out[q][b][h] = (E.V)/rowsum
  gemm97<3><<<dim3(16, 8, 4), 256, 0, stream>>>(E, SEQ, (long long)SEQ * SEQ,
                                                Vt, SEQ, (long long)HID * SEQ,
                                                partial, out, nullptr, SEQ);
}

// Round 13
// 183.661 us; speedup vs baseline: 1.0322x; 1.0322x over previous
//
#include <hip/hip_runtime.h>
#include <hip/hip_bf16.h>

#define SEQ 2048
#define BATCH 4
#define HID 1024

typedef __bf16 bf16x8 __attribute__((ext_vector_type(8)));
typedef float f32x4 __attribute__((ext_vector_type(4)));

__device__ __forceinline__ void gload_lds16(void* lds, const void* g) {
  __builtin_amdgcn_global_load_lds(
      (const __attribute__((address_space(1))) void*)g,
      (__attribute__((address_space(3))) void*)lds, 16, 0, 0);
}

// ---------------- merged prep: cast x, cast Wq/Wk/Wv, concat bias ----------------
__device__ __forceinline__ void cast8(const float* __restrict__ in,
                                      __bf16* __restrict__ out, int i) {
  const float4* p = (const float4*)in + (size_t)i * 2;
  float4 a = p[0], b = p[1];
  bf16x8 v;
  v[0] = (__bf16)a.x; v[1] = (__bf16)a.y; v[2] = (__bf16)a.z; v[3] = (__bf16)a.w;
  v[4] = (__bf16)b.x; v[5] = (__bf16)b.y; v[6] = (__bf16)b.z; v[7] = (__bf16)b.w;
  ((bf16x8*)out)[i] = v;
}

#define NX (SEQ * BATCH * HID / 8)   // 1,048,576
#define NWI (HID * HID / 8)          // 131,072

__global__ __launch_bounds__(256) void prep(const float* __restrict__ x,
                                            const float* __restrict__ Wq,
                                            const float* __restrict__ Wk,
                                            const float* __restrict__ Wv,
                                            const float* __restrict__ bq,
                                            const float* __restrict__ bk,
                                            const float* __restrict__ bv,
                                            __bf16* __restrict__ xbf,
                                            __bf16* __restrict__ wqkv,
                                            float* __restrict__ bqkv) {
  int id = blockIdx.x * 256 + threadIdx.x;
  if (id < NX) {
    cast8(x, xbf, id);
  } else if (id < NX + 3 * NWI) {
    const int j = id - NX;
    const int w = j / NWI, k = j - w * NWI;
    const float* src = w == 0 ? Wq : w == 1 ? Wk : Wv;
    cast8(src, wqkv + (size_t)w * HID * HID, k);
  } else if (id < NX + 3 * NWI + 3 * HID) {
    const int j = id - (NX + 3 * NWI);
    bqkv[j] = j < HID ? bq[j] : j < 2 * HID ? bk[j - HID] : bv[j - 2 * HID];
  }
}

// ====== 128x128xBK32 B^T GEMM, 4 waves (2x2), ring-3 (48KB) => 3 blocks/CU ======
// One barrier/K-tile; counted vmcnt(4) steady (0 only on last tile).
// PHASE-CLEAN swizzle (8-lane LDS service phases): LDS[row][j] holds global
// chunk (j - ((row>>1)&3)) & 3; read chunk j = (fq + (fr>>1)) & 3.
// Per 8-lane phase: 4 even-parity rows hit chunks {0,1,2,3} distinct (banks
// 0-15 once each) and 4 odd rows likewise (banks 16-31) -> all 32 banks
// exactly once -> 0 conflicts (model matches R6's measured 0 and R9/R12's
// measured 6 cyc/read).
// EPI 0: QKV, M flat 8192 (row = s*4+b); EPI 2: exp-scores + 16-wide partials;
// EPI 3: PV / rowsum.
#define SL 16384  // A 128x32x2 = 8KB | B 8KB
template<int EPI>
__global__ __launch_bounds__(256, 3)
void gemm97(const __bf16* __restrict__ A, int lda, long long sAz,
            const __bf16* __restrict__ B, int ldb, long long sBz,
            const float* __restrict__ aux, void* __restrict__ dst,
            float* __restrict__ aux2, int K)
{
  __shared__ __align__(16) char lds[3 * SL];
  const int tid = threadIdx.x;
  const int wid = tid >> 6, lane = tid & 63;
  const int wr = wid >> 1, wc = wid & 1;      // 2x2 wave grid, 64x64 tiles
  const int m0 = blockIdx.x * 128, n0 = blockIdx.y * 128;
  const int z = blockIdx.z;
  const __bf16* Ab = A + (size_t)z * sAz;
  const __bf16* Bb = B + (size_t)z * sBz;

  // staging: linear LDS dest (tid*16) = (row=tid>>2, chunk j=tid&3);
  // source global chunk = (j - ((row>>1)&3)) & 3, (row>>1)&3 == (tid>>3)&3
  const int srow = tid >> 2;                                        // 0..63
  const int scol = ((((tid & 3) - ((tid >> 3) & 3)) & 3)) * 16;     // source byte col
  const char* a0s = (const char*)(Ab + (size_t)(m0 + srow) * lda) + scol;
  const char* a1s = (const char*)(Ab + (size_t)(m0 + 64 + srow) * lda) + scol;
  const char* b0s = (const char*)(Bb + (size_t)(n0 + srow) * ldb) + scol;
  const char* b1s = (const char*)(Bb + (size_t)(n0 + 64 + srow) * ldb) + scol;
  const int dT = tid * 16;

  auto stage = [&](int slot, int t) {
    char* sb = lds + slot * SL;
    const size_t ko = (size_t)t * 64;          // BK=32 bf16 = 64 B
    gload_lds16(sb + dT, a0s + ko);
    gload_lds16(sb + 4096 + dT, a1s + ko);
    gload_lds16(sb + 8192 + dT, b0s + ko);
    gload_lds16(sb + 12288 + dT, b1s + ko);
  };

  // read: row*64 + ((fq + (fr>>1)) & 3) * 16   [(row>>1)&3 == (fr>>1)&3 here]
  const int fr = lane & 15, fq = lane >> 4;
  const int cc = ((fq + (fr >> 1)) & 3) * 16;
  int aoff[4], boff[4];
#pragma unroll
  for (int mi = 0; mi < 4; ++mi)
    aoff[mi] = (wr * 64 + mi * 16 + fr) * 64 + cc;
#pragma unroll
  for (int ni = 0; ni < 4; ++ni)
    boff[ni] = 8192 + (wc * 64 + ni * 16 + fr) * 64 + cc;

  const int nk = K >> 5;
  stage(0, 0);
  stage(1, 1);

  f32x4 acc[4][4] = {};
  for (int t = 0; t < nk; ++t) {
    char* s = lds + (t % 3) * SL;
    // drain tile t's 4 loads; keep tile t+1's in flight
    if (t + 1 < nk) asm volatile("s_waitcnt vmcnt(4)" ::: "memory");
    else            asm volatile("s_waitcnt vmcnt(0)" ::: "memory");
    __builtin_amdgcn_s_barrier();
    asm volatile("" ::: "memory");

    bf16x8 a[4], b[4];
#pragma unroll
    for (int mi = 0; mi < 4; ++mi) a[mi] = *(const bf16x8*)(s + aoff[mi]);
#pragma unroll
    for (int ni = 0; ni < 4; ++ni) b[ni] = *(const bf16x8*)(s + boff[ni]);

    // stage t+2 into slot (t+2)%3 == (t-1)%3: consumed reads provably complete
    if (t + 2 < nk) stage((t + 2) % 3, t + 2);

#pragma unroll
    for (int mi = 0; mi < 4; ++mi)
#pragma unroll
      for (int ni = 0; ni < 4; ++ni)
        acc[mi][ni] = __builtin_amdgcn_mfma_f32_16x16x32_bf16(a[mi], b[ni], acc[mi][ni], 0, 0, 0);
  }
  __syncthreads();  // all waves done (last tile waited vmcnt(0)) before LDS reuse

  // ---- epilogues; D frag: row=(lane>>4)*4+r, col=lane&15 ----
  if (EPI == 0) {
    const int hsel = n0 >> 10;  // block-uniform: 0=Q,1=K,2=V
    const size_t BSH = (size_t)BATCH * SEQ * HID;
#pragma unroll
    for (int mi = 0; mi < 4; ++mi) {
#pragma unroll
      for (int ni = 0; ni < 4; ++ni) {
        const int gn = n0 + wc * 64 + ni * 16 + fr;
        const int h = gn & (HID - 1);
        const int gmb = m0 + wr * 64 + mi * 16 + fq * 4;
        const float bias = aux[gn];
        f32x4 v = acc[mi][ni];
#pragma unroll
        for (int r = 0; r < 4; ++r) {
          const int gm = gmb + r;              // flat row = s*BATCH+b
          const int b = gm & 3, sfl = gm >> 2;
          if (hsel < 2)
            ((__bf16*)dst)[(size_t)hsel * BSH + (size_t)b * SEQ * HID +
                           (size_t)sfl * HID + h] = (__bf16)(v[r] + bias);
          else
            ((__bf16*)dst)[2 * BSH + (size_t)b * HID * SEQ +
                           (size_t)h * SEQ + sfl] = (__bf16)(v[r] + bias);
        }
      }
    }
  } else if (EPI == 2) {
    float psum[4][4] = {};
#pragma unroll
    for (int mi = 0; mi < 4; ++mi) {
#pragma unroll
      for (int ni = 0; ni < 4; ++ni) {
        const int gn = n0 + wc * 64 + ni * 16 + fr;
        const int gmb = m0 + wr * 64 + mi * 16 + fq * 4;
        f32x4 v = acc[mi][ni];
#pragma unroll
        for (int r = 0; r < 4; ++r) {
          const size_t idx = (size_t)z * SEQ * SEQ + (size_t)(gmb + r) * SEQ + gn;
          const float e = __expf(v[r] * 0.03125f * aux[idx]);
          ((__bf16*)dst)[idx] = (__bf16)e;
          psum[mi][r] += e;
        }
      }
    }
#pragma unroll
    for (int mi = 0; mi < 4; ++mi)
#pragma unroll
      for (int r = 0; r < 4; ++r) {
        float sv = psum[mi][r];
        sv += __shfl_xor(sv, 1); sv += __shfl_xor(sv, 2);
        sv += __shfl_xor(sv, 4); sv += __shfl_xor(sv, 8);
        psum[mi][r] = sv;
      }
    float* red = (float*)lds;   // [2 wc][128 rows]
    if (fr == 0) {
#pragma unroll
      for (int mi = 0; mi < 4; ++mi)
#pragma unroll
        for (int r = 0; r < 4; ++r)
          red[wc * 128 + wr * 64 + mi * 16 + fq * 4 + r] = psum[mi][r];
    }
    __syncthreads();
    if (tid < 128) {
      const float sv = red[tid] + red[128 + tid];
      aux2[((size_t)z * SEQ + m0 + tid) * 16 + blockIdx.y] = sv;
    }
  } else {  // EPI == 3
    float* red = (float*)lds;
    if (tid < 128) {
      const float* pp = aux + ((size_t)z * SEQ + m0 + tid) * 16;
      float sv = 0.f;
#pragma unroll
      for (int j = 0; j < 16; ++j) sv += pp[j];
      red[tid] = 1.f / sv;
    }
    __syncthreads();
#pragma unroll
    for (int mi = 0; mi < 4; ++mi) {
#pragma unroll
      for (int ni = 0; ni < 4; ++ni) {
        const int gn = n0 + wc * 64 + ni * 16 + fr;
        const int rbase = wr * 64 + mi * 16 + fq * 4;
        f32x4 v = acc[mi][ni];
#pragma unroll
        for (int r = 0; r < 4; ++r)
          ((float*)dst)[((size_t)(m0 + rbase + r) * BATCH + z) * HID + gn] = v[r] * red[rbase + r];
      }
    }
  }
}

extern "C" void kernel_launch(void* const* d_in, const int* in_sizes, int n_in,
                              void* d_out, int out_size, void* d_ws, size_t ws_size,
                              hipStream_t stream) {
  const float* x   = (const float*)d_in[0];
  const float* ssm = (const float*)d_in[1];
  const float* Wq  = (const float*)d_in[2];
  const float* bq  = (const float*)d_in[3];
  const float* Wk  = (const float*)d_in[4];
  const float* bk  = (const float*)d_in[5];
  const float* Wv  = (const float*)d_in[6];
  const float* bv  = (const float*)d_in[7];
  float* out = (float*)d_out;

  const size_t BSH = (size_t)BATCH * SEQ * HID;
  float* bqkv    = (float*)d_ws;                               // 4096 floats
  float* partial = bqkv + 4096;                                // BATCH*SEQ*16
  __bf16* xbf  = (__bf16*)(partial + (size_t)BATCH * SEQ * 16);
  __bf16* wqkv = xbf + BSH;
  __bf16* Qb = wqkv + (size_t)3 * HID * HID;                   // Q | K | Vt
  __bf16* Kb = Qb + BSH;
  __bf16* Vt = Qb + 2 * BSH;
  __bf16* E  = Qb + 3 * BSH;                                   // [b][q][k] bf16

  const int prep_items = NX + 3 * NWI + 3 * HID;
  prep<<<(prep_items + 255) / 256, 256, 0, stream>>>(x, Wq, Wk, Wv, bq, bk, bv,
                                                     xbf, wqkv, bqkv);

  // QKV: M = 8192 flat rows of xbf (row = s*4+b), N = 3072, K = 1024
  gemm97<0><<<dim3(64, 24, 1), 256, 0, stream>>>(xbf, HID, 0,
                                                 wqkv, HID, 0, bqkv, Qb, nullptr, HID);
  // scores: per z, 2048 x 2048 x 1024; E = exp(QK/32 * ssm) + row partials
  gemm97<2><<<dim3(16, 16, 4), 256, 0, stream>>>(Qb, HID, (long long)SEQ * HID,
                                                 Kb, HID, (long long)SEQ * HID,
                                                 ssm, E, partial, HID);
  // PV: per z, 2048 x 1024 x 2048; out[q][b][h] = (E.V)/rowsum
  gemm97<3><<<dim3(16, 8, 4), 256, 0, stream>>>(E, SEQ, (long long)SEQ * SEQ,
                                                Vt, SEQ, (long long)HID * SEQ,
                                                partial, out, nullptr, SEQ);
}

// Round 14
// 153.564 us; speedup vs baseline: 1.2345x; 1.1960x over previous
//
#include <hip/hip_runtime.h>
#include <hip/hip_bf16.h>

#define SEQ 2048
#define BATCH 4
#define HID 1024

typedef __bf16 bf16x8 __attribute__((ext_vector_type(8)));
typedef __bf16 bf16x4 __attribute__((ext_vector_type(4)));
typedef float f32x4 __attribute__((ext_vector_type(4)));

__device__ __forceinline__ void gload_lds16(void* lds, const void* g) {
  __builtin_amdgcn_global_load_lds(
      (const __attribute__((address_space(1))) void*)g,
      (__attribute__((address_space(3))) void*)lds, 16, 0, 0);
}

// ---------------- merged prep: cast x, cast Wq/Wk/Wv, concat bias ----------------
__device__ __forceinline__ void cast8(const float* __restrict__ in,
                                      __bf16* __restrict__ out, int i) {
  const float4* p = (const float4*)in + (size_t)i * 2;
  float4 a = p[0], b = p[1];
  bf16x8 v;
  v[0] = (__bf16)a.x; v[1] = (__bf16)a.y; v[2] = (__bf16)a.z; v[3] = (__bf16)a.w;
  v[4] = (__bf16)b.x; v[5] = (__bf16)b.y; v[6] = (__bf16)b.z; v[7] = (__bf16)b.w;
  ((bf16x8*)out)[i] = v;
}

#define NX (SEQ * BATCH * HID / 8)   // 1,048,576
#define NWI (HID * HID / 8)          // 131,072

__global__ __launch_bounds__(256) void prep(const float* __restrict__ x,
                                            const float* __restrict__ Wq,
                                            const float* __restrict__ Wk,
                                            const float* __restrict__ Wv,
                                            const float* __restrict__ bq,
                                            const float* __restrict__ bk,
                                            const float* __restrict__ bv,
                                            __bf16* __restrict__ xbf,
                                            __bf16* __restrict__ wqkv,
                                            float* __restrict__ bqkv) {
  int id = blockIdx.x * 256 + threadIdx.x;
  if (id < NX) {
    cast8(x, xbf, id);
  } else if (id < NX + 3 * NWI) {
    const int j = id - NX;
    const int w = j / NWI, k = j - w * NWI;
    const float* src = w == 0 ? Wq : w == 1 ? Wk : Wv;
    cast8(src, wqkv + (size_t)w * HID * HID, k);
  } else if (id < NX + 3 * NWI + 3 * HID) {
    const int j = id - (NX + 3 * NWI);
    bqkv[j] = j < HID ? bq[j] : j < 2 * HID ? bk[j - HID] : bv[j - 2 * HID];
  }
}

// ============ 8-wave 128x256xK B^T GEMM, 3-slot ring, counted vmcnt ============
// R6-verified core: one barrier/K-tile, vmcnt(6) steady (0 only on last tile),
// XOR swizzle (0 bank conflicts), stage t+2 after the barrier. No block swizzle
// (T1 regressed: operands L2/L3-resident, R10).
// EPI 0: QKV proj; aux=bias[3072]; Q/K -> [z][s][h]+bias, V -> [z][h][s]+bias
// EPI 2: e=exp(acc/32*ssm) -> bf16 [z][q][k]; row partials -> aux2[row*8+by]
// EPI 3: out[(q*BATCH+z)*HID+h] = acc / rowsum(aux)
#define SLOT 49152  // A 128x64x2 = 16384 B, B 256x64x2 = 32768 B
template<int EPI>
__global__ __launch_bounds__(512, 2)
void gemm8(const __bf16* __restrict__ A, int lda, long long sAz,
           const __bf16* __restrict__ B, int ldb, long long sBz,
           const float* __restrict__ aux, void* __restrict__ dst,
           float* __restrict__ aux2, int K)
{
  __shared__ __align__(16) char lds[3 * SLOT];
  const int tid = threadIdx.x;
  const int wid = tid >> 6, lane = tid & 63;
  const int wr = wid >> 2, wc = wid & 3;   // 2 x 4 wave grid (64x64 tiles)
  const int m0 = blockIdx.x * 128, n0 = blockIdx.y * 256;
  const int z = blockIdx.z;
  const __bf16* Ab = A + (size_t)z * sAz;
  const __bf16* Bb = B + (size_t)z * sBz;

  // ---- staging: linear LDS dest, inverse-swizzled global source ----
  const int srow = tid >> 3;                                  // 0..63
  const int scol = ((tid & 7) * 16) ^ ((srow & 7) << 4);      // swizzled byte col
  const char* asrc0 = (const char*)(Ab + (size_t)(m0 + srow) * lda) + scol;
  const char* asrc1 = (const char*)(Ab + (size_t)(m0 + srow + 64) * lda) + scol;
  const char* bsrc0 = (const char*)(Bb + (size_t)(n0 + srow) * ldb) + scol;
  const char* bsrc1 = (const char*)(Bb + (size_t)(n0 + srow + 64) * ldb) + scol;
  const char* bsrc2 = (const char*)(Bb + (size_t)(n0 + srow + 128) * ldb) + scol;
  const char* bsrc3 = (const char*)(Bb + (size_t)(n0 + srow + 192) * ldb) + scol;
  const int dA = tid * 16, dB = 16384 + tid * 16;

  // ---- swizzled ds_read offsets ----
  const int fr = lane & 15, fq = lane >> 4;
  const int fc2 = fq * 16;
  const int swz = (fr & 7) << 4;
  int aoff[4][2], boff[4][2];
#pragma unroll
  for (int mi = 0; mi < 4; ++mi) {
    const int row = wr * 64 + mi * 16 + fr;
#pragma unroll
    for (int ks = 0; ks < 2; ++ks)
      aoff[mi][ks] = row * 128 + ((fc2 + ks * 64) ^ swz);
  }
#pragma unroll
  for (int ni = 0; ni < 4; ++ni) {
    const int row = wc * 64 + ni * 16 + fr;
#pragma unroll
    for (int ks = 0; ks < 2; ++ks)
      boff[ni][ks] = 16384 + row * 128 + ((fc2 + ks * 64) ^ swz);
  }

  const int nk = K >> 6;
  // prologue: fully stage tiles 0 and 1 (12 loads in flight)
  {
    char* s0 = lds;
    gload_lds16(s0 + dA, asrc0); gload_lds16(s0 + dA + 8192, asrc1);
    gload_lds16(s0 + dB, bsrc0); gload_lds16(s0 + dB + 8192, bsrc1);
    gload_lds16(s0 + dB + 16384, bsrc2); gload_lds16(s0 + dB + 24576, bsrc3);
    char* s1 = lds + SLOT;
    gload_lds16(s1 + dA, asrc0 + 128); gload_lds16(s1 + dA + 8192, asrc1 + 128);
    gload_lds16(s1 + dB, bsrc0 + 128); gload_lds16(s1 + dB + 8192, bsrc1 + 128);
    gload_lds16(s1 + dB + 16384, bsrc2 + 128); gload_lds16(s1 + dB + 24576, bsrc3 + 128);
  }

  f32x4 acc[4][4] = {};
  for (int t = 0; t < nk; ++t) {
    char* s = lds + (t % 3) * SLOT;
    // tile t's loads done (t+1's 6 stay in flight); all waves' t-1 reads done
    if (t + 1 < nk) asm volatile("s_waitcnt vmcnt(6)" ::: "memory");
    else            asm volatile("s_waitcnt vmcnt(0)" ::: "memory");
    __builtin_amdgcn_s_barrier();
    asm volatile("" ::: "memory");

    bf16x8 a[4][2], b[4][2];
#pragma unroll
    for (int mi = 0; mi < 4; ++mi)
#pragma unroll
      for (int ks = 0; ks < 2; ++ks)
        a[mi][ks] = *(const bf16x8*)(s + aoff[mi][ks]);
#pragma unroll
    for (int ni = 0; ni < 4; ++ni)
#pragma unroll
      for (int ks = 0; ks < 2; ++ks)
        b[ni][ks] = *(const bf16x8*)(s + boff[ni][ks]);

    // prefetch tile t+2 into slot (t+2)%3 (== slot of t-1; safe past the barrier)
    if (t + 2 < nk) {
      char* sn = lds + ((t + 2) % 3) * SLOT;
      const size_t ko = (size_t)(t + 2) * 128;
      gload_lds16(sn + dA, asrc0 + ko);
      gload_lds16(sn + dA + 8192, asrc1 + ko);
      gload_lds16(sn + dB, bsrc0 + ko);
      gload_lds16(sn + dB + 8192, bsrc1 + ko);
      gload_lds16(sn + dB + 16384, bsrc2 + ko);
      gload_lds16(sn + dB + 24576, bsrc3 + ko);
    }

    __builtin_amdgcn_s_setprio(1);
#pragma unroll
    for (int mi = 0; mi < 4; ++mi)
#pragma unroll
      for (int ni = 0; ni < 4; ++ni)
#pragma unroll
        for (int ks = 0; ks < 2; ++ks)
          acc[mi][ni] = __builtin_amdgcn_mfma_f32_16x16x32_bf16(a[mi][ks], b[ni][ks], acc[mi][ni], 0, 0, 0);
    __builtin_amdgcn_s_setprio(0);
    // next tile-top provides vmcnt + barrier
  }
  __syncthreads();  // full drain before LDS reuse in epilogues

  // ---- epilogues; D frag: row=(lane>>4)*4+r, col=lane&15 ----
  if (EPI == 0) {
    const int hsel = n0 >> 10;  // block-uniform: 0=Q,1=K,2=V
    const size_t BSH = (size_t)BATCH * SEQ * HID;
#pragma unroll
    for (int mi = 0; mi < 4; ++mi) {
#pragma unroll
      for (int ni = 0; ni < 4; ++ni) {
        const int gn = n0 + wc * 64 + ni * 16 + fr;
        const int h = gn & (HID - 1);
        const int gmb = m0 + wr * 64 + mi * 16 + fq * 4;
        const float bias = aux[gn];
        f32x4 v = acc[mi][ni];
        if (hsel < 2) {
#pragma unroll
          for (int r = 0; r < 4; ++r)
            ((__bf16*)dst)[(size_t)hsel * BSH + (size_t)z * SEQ * HID +
                           (size_t)(gmb + r) * HID + h] = (__bf16)(v[r] + bias);
        } else {
          bf16x4 vv;
#pragma unroll
          for (int r = 0; r < 4; ++r) vv[r] = (__bf16)(v[r] + bias);
          *(bf16x4*)&((__bf16*)dst)[2 * BSH + (size_t)z * HID * SEQ +
                                    (size_t)h * SEQ + gmb] = vv;
        }
      }
    }
  } else if (EPI == 2) {
    float psum[4][4] = {};
#pragma unroll
    for (int mi = 0; mi < 4; ++mi) {
#pragma unroll
      for (int ni = 0; ni < 4; ++ni) {
        const int gn = n0 + wc * 64 + ni * 16 + fr;
        const int gmb = m0 + wr * 64 + mi * 16 + fq * 4;
        f32x4 v = acc[mi][ni];
#pragma unroll
        for (int r = 0; r < 4; ++r) {
          const size_t idx = (size_t)z * SEQ * SEQ + (size_t)(gmb + r) * SEQ + gn;
          const float e = __expf(v[r] * 0.03125f * aux[idx]);
          ((__bf16*)dst)[idx] = (__bf16)e;
          psum[mi][r] += e;
        }
      }
    }
    // reduce over the 16 fr lanes
#pragma unroll
    for (int mi = 0; mi < 4; ++mi)
#pragma unroll
      for (int r = 0; r < 4; ++r) {
        float sv = psum[mi][r];
        sv += __shfl_xor(sv, 1); sv += __shfl_xor(sv, 2);
        sv += __shfl_xor(sv, 4); sv += __shfl_xor(sv, 8);
        psum[mi][r] = sv;
      }
    float* red = (float*)lds;  // 8 waves x 64 rows
    if (fr == 0) {
#pragma unroll
      for (int mi = 0; mi < 4; ++mi)
#pragma unroll
        for (int r = 0; r < 4; ++r)
          red[wid * 64 + mi * 16 + fq * 4 + r] = psum[mi][r];
    }
    __syncthreads();
    if (tid < 128) {
      const int half = tid >> 6, r64 = tid & 63;
      float sv = 0.f;
#pragma unroll
      for (int j = 0; j < 4; ++j) sv += red[(half * 4 + j) * 64 + r64];
      aux2[((size_t)z * SEQ + m0 + tid) * 8 + blockIdx.y] = sv;
    }
  } else {  // EPI == 3
    float* red = (float*)lds;
    if (tid < 128) {
      const float* pp = aux + ((size_t)z * SEQ + m0 + tid) * 8;
      float sv = 0.f;
#pragma unroll
      for (int j = 0; j < 8; ++j) sv += pp[j];
      red[tid] = 1.f / sv;
    }
    __syncthreads();
#pragma unroll
    for (int mi = 0; mi < 4; ++mi) {
#pragma unroll
      for (int ni = 0; ni < 4; ++ni) {
        const int gn = n0 + wc * 64 + ni * 16 + fr;
        const int rbase = wr * 64 + mi * 16 + fq * 4;
        f32x4 v = acc[mi][ni];
#pragma unroll
        for (int r = 0; r < 4; ++r)
          ((float*)dst)[((size_t)(m0 + rbase + r) * BATCH + z) * HID + gn] = v[r] * red[rbase + r];
      }
    }
  }
}

extern "C" void kernel_launch(void* const* d_in, const int* in_sizes, int n_in,
                              void* d_out, int out_size, void* d_ws, size_t ws_size,
                              hipStream_t stream) {
  const float* x   = (const float*)d_in[0];
  const float* ssm = (const float*)d_in[1];
  const float* Wq  = (const float*)d_in[2];
  const float* bq  = (const float*)d_in[3];
  const float* Wk  = (const float*)d_in[4];
  const float* bk  = (const float*)d_in[5];
  const float* Wv  = (const float*)d_in[6];
  const float* bv  = (const float*)d_in[7];
  float* out = (float*)d_out;

  const size_t BSH = (size_t)BATCH * SEQ * HID;
  float* bqkv    = (float*)d_ws;                               // 4096 floats
  float* partial = bqkv + 4096;                                // BATCH*SEQ*8
  __bf16* xbf  = (__bf16*)(partial + (size_t)BATCH * SEQ * 8);
  __bf16* wqkv = xbf + BSH;
  __bf16* Qb = wqkv + (size_t)3 * HID * HID;                   // Q | K | Vt
  __bf16* Kb = Qb + BSH;
  __bf16* Vt = Qb + 2 * BSH;
  __bf16* E  = Qb + 3 * BSH;                                   // [b][q][k] bf16

  const int prep_items = NX + 3 * NWI + 3 * HID;
  prep<<<(prep_items + 255) / 256, 256, 0, stream>>>(x, Wq, Wk, Wv, bq, bk, bv,
                                                     xbf, wqkv, bqkv);

  // QKV: A = per-batch view of x (lda BATCH*HID), B = wqkv [3072][1024]
  gemm8<0><<<dim3(16, 12, BATCH), 512, 0, stream>>>(xbf, BATCH * HID, HID,
                                                    wqkv, HID, 0, bqkv, Qb, nullptr, HID);
  // scores: E = exp(Q.K/32 * ssm), partial row sums
  gemm8<2><<<dim3(16, 8, BATCH), 512, 0, stream>>>(Qb, HID, (long long)SEQ * HID,
                                                   Kb, HID, (long long)SEQ * HID,
                                                   ssm, E, partial, HID);
  // PV: out[q][b][h] = (E.V) / rowsum
  gemm8<3><<<dim3(16, 4, BATCH), 512, 0, stream>>>(E, SEQ, (long long)SEQ * SEQ,
                                                   Vt, SEQ, (long long)HID * SEQ,
                                                   partial, out, nullptr, SEQ);
}